// Round 14
// baseline (406.833 us; speedup 1.0000x reference)
//
#include <hip/hip_runtime.h>
#include <math.h>

#define NTOK 1024
#define DDIM 512

using short8 = __attribute__((ext_vector_type(8))) short;
using f32x4  = __attribute__((ext_vector_type(4))) float;

__device__ __forceinline__ float4 ld4(const float* p){ return *(const float4*)p; }
__device__ __forceinline__ void st4(float* p, float4 v){ *(float4*)p = v; }
__device__ __forceinline__ unsigned short bf16r(float x) {
  unsigned int u = __float_as_uint(x);
  u += 0x7fffu + ((u >> 16) & 1u);
  return (unsigned short)(u >> 16);
}
__device__ __forceinline__ float bf16f(unsigned short h) {
  return __uint_as_float(((unsigned int)h) << 16);
}
__device__ __forceinline__ f32x4 mfma16(short8 a, short8 b, f32x4 c) {
  return __builtin_amdgcn_mfma_f32_16x16x32_bf16(a, b, c, 0, 0, 0);
}

// ---------------- LayerNorm over D=512 with affine, fp32 out ----------------
__global__ __launch_bounds__(256) void ln_rows(const float* __restrict__ x,
    const float* __restrict__ w, const float* __restrict__ b, float* __restrict__ y) {
  int row = blockIdx.x, t = threadIdx.x;
  const float* xr = x + ((size_t)row << 9);
  float v0 = xr[t], v1 = xr[t + 256];
  float s = v0 + v1, q = v0*v0 + v1*v1;
  #pragma unroll
  for (int off = 1; off < 64; off <<= 1) { s += __shfl_xor(s, off); q += __shfl_xor(q, off); }
  __shared__ float ls[4], lq[4], mb[2];
  int wv = t >> 6;
  if ((t & 63) == 0) { ls[wv] = s; lq[wv] = q; }
  __syncthreads();
  if (t == 0) {
    float S = ls[0]+ls[1]+ls[2]+ls[3];
    float Q = lq[0]+lq[1]+lq[2]+lq[3];
    float m = S * (1.f/512.f);
    float var = Q * (1.f/512.f) - m*m;
    mb[0] = m; mb[1] = 1.f / sqrtf(var + 1e-5f);
  }
  __syncthreads();
  float m = mb[0], inv = mb[1];
  float* yr = y + ((size_t)row << 9);
  yr[t]       = (v0 - m) * inv * w[t] + b[t];
  yr[t + 256] = (v1 - m) * inv * w[t + 256] + b[t + 256];
}

// ---- fused: v = pa+pb+hin; write v (residual) and LN(v) ----
__global__ __launch_bounds__(256) void ln_rows3(const float* __restrict__ pa,
    const float* __restrict__ pb, const float* __restrict__ hi,
    const float* __restrict__ w, const float* __restrict__ b,
    float* __restrict__ hsum, float* __restrict__ y) {
  int row = blockIdx.x, t = threadIdx.x;
  size_t base = ((size_t)row << 9);
  float v0 = pa[base + t] + pb[base + t] + hi[base + t];
  float v1 = pa[base + t + 256] + pb[base + t + 256] + hi[base + t + 256];
  float s = v0 + v1, q = v0*v0 + v1*v1;
  #pragma unroll
  for (int off = 1; off < 64; off <<= 1) { s += __shfl_xor(s, off); q += __shfl_xor(q, off); }
  __shared__ float ls[4], lq[4], mb[2];
  int wv = t >> 6;
  if ((t & 63) == 0) { ls[wv] = s; lq[wv] = q; }
  __syncthreads();
  if (t == 0) {
    float S = ls[0]+ls[1]+ls[2]+ls[3];
    float Q = lq[0]+lq[1]+lq[2]+lq[3];
    float m = S * (1.f/512.f);
    float var = Q * (1.f/512.f) - m*m;
    mb[0] = m; mb[1] = 1.f / sqrtf(var + 1e-5f);
  }
  __syncthreads();
  float m = mb[0], inv = mb[1];
  hsum[base + t] = v0;
  hsum[base + t + 256] = v1;
  y[base + t]       = (v0 - m) * inv * w[t] + b[t];
  y[base + t + 256] = (v1 - m) * inv * w[t + 256] + b[t + 256];
}

// ------- convert + transpose + hi/lo split (multi-weight via blockIdx.z) -------
struct C4 {
  const float *S0, *S1, *S2, *S3;
  unsigned short *D0, *D1, *D2, *D3;
};
__global__ __launch_bounds__(256) void convT(C4 p, int K, int N) {
  __shared__ unsigned short Th[64][68];
  __shared__ unsigned short Tl[64][68];
  int z = blockIdx.z;
  const float* src = (z==0)?p.S0:(z==1)?p.S1:(z==2)?p.S2:p.S3;
  unsigned short* dst = (z==0)?p.D0:(z==1)?p.D1:(z==2)?p.D2:p.D3;
  int nt = blockIdx.x << 6, kt = blockIdx.y << 6;
  int t = threadIdx.x;
  int r = t >> 4, c4 = (t & 15) << 2;
  #pragma unroll
  for (int pp = 0; pp < 4; ++pp) {
    int kk = r + (pp << 4);
    float4 v = ld4(src + (size_t)(kt + kk) * N + nt + c4);
    float vv[4] = {v.x, v.y, v.z, v.w};
    #pragma unroll
    for (int i = 0; i < 4; ++i) {
      unsigned short h = bf16r(vv[i]);
      Th[c4 + i][kk] = h;
      Tl[c4 + i][kk] = bf16r(vv[i] - bf16f(h));
    }
  }
  __syncthreads();
  size_t loff = (size_t)N * K;
  #pragma unroll
  for (int pp = 0; pp < 4; ++pp) {
    int nn = r + (pp << 4);
    ushort4 oh, ol;
    oh.x = Th[nn][c4]; oh.y = Th[nn][c4+1]; oh.z = Th[nn][c4+2]; oh.w = Th[nn][c4+3];
    ol.x = Tl[nn][c4]; ol.y = Tl[nn][c4+1]; ol.z = Tl[nn][c4+2]; ol.w = Tl[nn][c4+3];
    *(ushort4*)(dst + (size_t)(nt + nn) * K + kt + c4) = oh;
    *(ushort4*)(dst + loff + (size_t)(nt + nn) * K + kt + c4) = ol;
  }
}

// ---------------- split-precision bf16 MFMA GEMM ----------------
struct P4 {
  const unsigned short *W0, *W1, *W2, *W3;
  float *C0, *C1, *C2, *C3;
};
template<int MODE>
__global__ __launch_bounds__(256) void gemm_mfma(const float* __restrict__ A,
    P4 p, int Kd, int Nd, int kwin) {
  __shared__ unsigned short Ash[64][72];
  __shared__ unsigned short Asl[64][72];
  __shared__ unsigned short Bsh[64][72];
  __shared__ unsigned short Bsl[64][72];
  int t = threadIdx.x;
  int z = blockIdx.z;
  const unsigned short* W = (z==0)?p.W0:(z==1)?p.W1:(z==2)?p.W2:p.W3;
  float* C = (z==0)?p.C0:(z==1)?p.C1:(z==2)?p.C2:p.C3;
  const unsigned short* Wl = W + (size_t)Nd * Kd;
  int bm = blockIdx.y << 6, bn = blockIdx.x << 6;
  int wid = t >> 6, lane = t & 63;
  int wm = wid >> 1, wn = wid & 1;
  int lr = lane & 15, lk = lane >> 4;
  int r0 = t >> 3, ks = (t & 7) << 3;
  int kbeg = kwin ? z * kwin : 0;
  int kend = kwin ? kbeg + kwin : Kd;
  f32x4 acc[2][2];
  #pragma unroll
  for (int i = 0; i < 2; ++i)
    #pragma unroll
    for (int j = 0; j < 2; ++j)
      #pragma unroll
      for (int r = 0; r < 4; ++r) acc[i][j][r] = 0.f;
  for (int k0 = kbeg; k0 < kend; k0 += 64) {
    float4 a00 = ld4(A + (size_t)(bm + r0) * Kd + k0 + ks);
    float4 a01 = ld4(A + (size_t)(bm + r0) * Kd + k0 + ks + 4);
    float4 a10 = ld4(A + (size_t)(bm + r0 + 32) * Kd + k0 + ks);
    float4 a11 = ld4(A + (size_t)(bm + r0 + 32) * Kd + k0 + ks + 4);
    uint4 b0h = *(const uint4*)(W  + (size_t)(bn + r0) * Kd + k0 + ks);
    uint4 b1h = *(const uint4*)(W  + (size_t)(bn + r0 + 32) * Kd + k0 + ks);
    uint4 b0l = *(const uint4*)(Wl + (size_t)(bn + r0) * Kd + k0 + ks);
    uint4 b1l = *(const uint4*)(Wl + (size_t)(bn + r0 + 32) * Kd + k0 + ks);
    __syncthreads();
    {
      float va[8] = {a00.x,a00.y,a00.z,a00.w,a01.x,a01.y,a01.z,a01.w};
      short8 h8, l8;
      #pragma unroll
      for (int i = 0; i < 8; ++i) {
        unsigned short h = bf16r(va[i]);
        h8[i] = (short)h; l8[i] = (short)bf16r(va[i] - bf16f(h));
      }
      *(short8*)&Ash[r0][ks] = h8;
      *(short8*)&Asl[r0][ks] = l8;
    }
    {
      float va[8] = {a10.x,a10.y,a10.z,a10.w,a11.x,a11.y,a11.z,a11.w};
      short8 h8, l8;
      #pragma unroll
      for (int i = 0; i < 8; ++i) {
        unsigned short h = bf16r(va[i]);
        h8[i] = (short)h; l8[i] = (short)bf16r(va[i] - bf16f(h));
      }
      *(short8*)&Ash[r0 + 32][ks] = h8;
      *(short8*)&Asl[r0 + 32][ks] = l8;
    }
    *(uint4*)&Bsh[r0][ks] = b0h;
    *(uint4*)&Bsh[r0 + 32][ks] = b1h;
    *(uint4*)&Bsl[r0][ks] = b0l;
    *(uint4*)&Bsl[r0 + 32][ks] = b1l;
    __syncthreads();
    #pragma unroll
    for (int s = 0; s < 2; ++s) {
      short8 ah0 = *(const short8*)&Ash[wm*32 + lr][s*32 + lk*8];
      short8 ah1 = *(const short8*)&Ash[wm*32 + 16 + lr][s*32 + lk*8];
      short8 al0 = *(const short8*)&Asl[wm*32 + lr][s*32 + lk*8];
      short8 al1 = *(const short8*)&Asl[wm*32 + 16 + lr][s*32 + lk*8];
      short8 bh0 = *(const short8*)&Bsh[wn*32 + lr][s*32 + lk*8];
      short8 bh1 = *(const short8*)&Bsh[wn*32 + 16 + lr][s*32 + lk*8];
      short8 bl0 = *(const short8*)&Bsl[wn*32 + lr][s*32 + lk*8];
      short8 bl1 = *(const short8*)&Bsl[wn*32 + 16 + lr][s*32 + lk*8];
      acc[0][0] = mfma16(ah0, bh0, acc[0][0]);
      acc[0][1] = mfma16(ah0, bh1, acc[0][1]);
      acc[1][0] = mfma16(ah1, bh0, acc[1][0]);
      acc[1][1] = mfma16(ah1, bh1, acc[1][1]);
      acc[0][0] = mfma16(al0, bh0, acc[0][0]);
      acc[0][1] = mfma16(al0, bh1, acc[0][1]);
      acc[1][0] = mfma16(al1, bh0, acc[1][0]);
      acc[1][1] = mfma16(al1, bh1, acc[1][1]);
      acc[0][0] = mfma16(ah0, bl0, acc[0][0]);
      acc[0][1] = mfma16(ah0, bl1, acc[0][1]);
      acc[1][0] = mfma16(ah1, bl0, acc[1][0]);
      acc[1][1] = mfma16(ah1, bl1, acc[1][1]);
    }
  }
  #pragma unroll
  for (int fm = 0; fm < 2; ++fm)
    #pragma unroll
    for (int fn = 0; fn < 2; ++fn) {
      int n = bn + wn*32 + fn*16 + lr;
      #pragma unroll
      for (int r = 0; r < 4; ++r) {
        int m = bm + wm*32 + fm*16 + lk*4 + r;
        float v = acc[fm][fn][r];
        if (MODE == 0) {
          if (z < 3) C[(((size_t)(n >> 5) << 10) + m) * 32 + (n & 31)] = v;
          else       C[(size_t)m * Nd + n] = v;
        } else {
          C[(size_t)m * Nd + n] = v;
        }
      }
    }
}

// ---- dual-weight W1/W3 GEMM with fused silu(p1)*p3 epilogue (K=512, N=2048) ----
__global__ __launch_bounds__(256) void gemm_w13(const float* __restrict__ A,
    const unsigned short* __restrict__ W1T, const unsigned short* __restrict__ W3T,
    float* __restrict__ AB) {
  __shared__ unsigned short Ash[64][72];
  __shared__ unsigned short Asl[64][72];
  __shared__ unsigned short B1h[64][72];
  __shared__ unsigned short B1l[64][72];
  __shared__ unsigned short B3h[64][72];
  __shared__ unsigned short B3l[64][72];
  const int Kd = 512, Nd = 2048;
  int t = threadIdx.x;
  const unsigned short* W1l = W1T + (size_t)Nd * Kd;
  const unsigned short* W3l = W3T + (size_t)Nd * Kd;
  int bm = blockIdx.y << 6, bn = blockIdx.x << 6;
  int wid = t >> 6, lane = t & 63;
  int wm = wid >> 1, wn = wid & 1;
  int lr = lane & 15, lk = lane >> 4;
  int r0 = t >> 3, ks = (t & 7) << 3;
  f32x4 acc1[2][2], acc3[2][2];
  #pragma unroll
  for (int i = 0; i < 2; ++i)
    #pragma unroll
    for (int j = 0; j < 2; ++j)
      #pragma unroll
      for (int r = 0; r < 4; ++r) { acc1[i][j][r] = 0.f; acc3[i][j][r] = 0.f; }
  for (int k0 = 0; k0 < Kd; k0 += 64) {
    float4 a00 = ld4(A + (size_t)(bm + r0) * Kd + k0 + ks);
    float4 a01 = ld4(A + (size_t)(bm + r0) * Kd + k0 + ks + 4);
    float4 a10 = ld4(A + (size_t)(bm + r0 + 32) * Kd + k0 + ks);
    float4 a11 = ld4(A + (size_t)(bm + r0 + 32) * Kd + k0 + ks + 4);
    uint4 c0h = *(const uint4*)(W1T + (size_t)(bn + r0) * Kd + k0 + ks);
    uint4 c1h = *(const uint4*)(W1T + (size_t)(bn + r0 + 32) * Kd + k0 + ks);
    uint4 c0l = *(const uint4*)(W1l + (size_t)(bn + r0) * Kd + k0 + ks);
    uint4 c1l = *(const uint4*)(W1l + (size_t)(bn + r0 + 32) * Kd + k0 + ks);
    uint4 d0h = *(const uint4*)(W3T + (size_t)(bn + r0) * Kd + k0 + ks);
    uint4 d1h = *(const uint4*)(W3T + (size_t)(bn + r0 + 32) * Kd + k0 + ks);
    uint4 d0l = *(const uint4*)(W3l + (size_t)(bn + r0) * Kd + k0 + ks);
    uint4 d1l = *(const uint4*)(W3l + (size_t)(bn + r0 + 32) * Kd + k0 + ks);
    __syncthreads();
    {
      float va[8] = {a00.x,a00.y,a00.z,a00.w,a01.x,a01.y,a01.z,a01.w};
      short8 h8, l8;
      #pragma unroll
      for (int i = 0; i < 8; ++i) {
        unsigned short h = bf16r(va[i]);
        h8[i] = (short)h; l8[i] = (short)bf16r(va[i] - bf16f(h));
      }
      *(short8*)&Ash[r0][ks] = h8;
      *(short8*)&Asl[r0][ks] = l8;
    }
    {
      float va[8] = {a10.x,a10.y,a10.z,a10.w,a11.x,a11.y,a11.z,a11.w};
      short8 h8, l8;
      #pragma unroll
      for (int i = 0; i < 8; ++i) {
        unsigned short h = bf16r(va[i]);
        h8[i] = (short)h; l8[i] = (short)bf16r(va[i] - bf16f(h));
      }
      *(short8*)&Ash[r0 + 32][ks] = h8;
      *(short8*)&Asl[r0 + 32][ks] = l8;
    }
    *(uint4*)&B1h[r0][ks] = c0h;  *(uint4*)&B1h[r0 + 32][ks] = c1h;
    *(uint4*)&B1l[r0][ks] = c0l;  *(uint4*)&B1l[r0 + 32][ks] = c1l;
    *(uint4*)&B3h[r0][ks] = d0h;  *(uint4*)&B3h[r0 + 32][ks] = d1h;
    *(uint4*)&B3l[r0][ks] = d0l;  *(uint4*)&B3l[r0 + 32][ks] = d1l;
    __syncthreads();
    #pragma unroll
    for (int s = 0; s < 2; ++s) {
      short8 ah0 = *(const short8*)&Ash[wm*32 + lr][s*32 + lk*8];
      short8 ah1 = *(const short8*)&Ash[wm*32 + 16 + lr][s*32 + lk*8];
      short8 al0 = *(const short8*)&Asl[wm*32 + lr][s*32 + lk*8];
      short8 al1 = *(const short8*)&Asl[wm*32 + 16 + lr][s*32 + lk*8];
      short8 p0h = *(const short8*)&B1h[wn*32 + lr][s*32 + lk*8];
      short8 p1h = *(const short8*)&B1h[wn*32 + 16 + lr][s*32 + lk*8];
      short8 p0l = *(const short8*)&B1l[wn*32 + lr][s*32 + lk*8];
      short8 p1l = *(const short8*)&B1l[wn*32 + 16 + lr][s*32 + lk*8];
      acc1[0][0] = mfma16(ah0, p0h, acc1[0][0]);
      acc1[0][1] = mfma16(ah0, p1h, acc1[0][1]);
      acc1[1][0] = mfma16(ah1, p0h, acc1[1][0]);
      acc1[1][1] = mfma16(ah1, p1h, acc1[1][1]);
      acc1[0][0] = mfma16(al0, p0h, acc1[0][0]);
      acc1[0][1] = mfma16(al0, p1h, acc1[0][1]);
      acc1[1][0] = mfma16(al1, p0h, acc1[1][0]);
      acc1[1][1] = mfma16(al1, p1h, acc1[1][1]);
      acc1[0][0] = mfma16(ah0, p0l, acc1[0][0]);
      acc1[0][1] = mfma16(ah0, p1l, acc1[0][1]);
      acc1[1][0] = mfma16(ah1, p0l, acc1[1][0]);
      acc1[1][1] = mfma16(ah1, p1l, acc1[1][1]);
      short8 q0h = *(const short8*)&B3h[wn*32 + lr][s*32 + lk*8];
      short8 q1h = *(const short8*)&B3h[wn*32 + 16 + lr][s*32 + lk*8];
      short8 q0l = *(const short8*)&B3l[wn*32 + lr][s*32 + lk*8];
      short8 q1l = *(const short8*)&B3l[wn*32 + 16 + lr][s*32 + lk*8];
      acc3[0][0] = mfma16(ah0, q0h, acc3[0][0]);
      acc3[0][1] = mfma16(ah0, q1h, acc3[0][1]);
      acc3[1][0] = mfma16(ah1, q0h, acc3[1][0]);
      acc3[1][1] = mfma16(ah1, q1h, acc3[1][1]);
      acc3[0][0] = mfma16(al0, q0h, acc3[0][0]);
      acc3[0][1] = mfma16(al0, q1h, acc3[0][1]);
      acc3[1][0] = mfma16(al1, q0h, acc3[1][0]);
      acc3[1][1] = mfma16(al1, q1h, acc3[1][1]);
      acc3[0][0] = mfma16(ah0, q0l, acc3[0][0]);
      acc3[0][1] = mfma16(ah0, q1l, acc3[0][1]);
      acc3[1][0] = mfma16(ah1, q0l, acc3[1][0]);
      acc3[1][1] = mfma16(ah1, q1l, acc3[1][1]);
    }
  }
  #pragma unroll
  for (int fm = 0; fm < 2; ++fm)
    #pragma unroll
    for (int fn = 0; fn < 2; ++fn) {
      int n = bn + wn*32 + fn*16 + lr;
      #pragma unroll
      for (int r = 0; r < 4; ++r) {
        int m = bm + wm*32 + fm*16 + lk*4 + r;
        float p1 = acc1[fm][fn][r];
        float p3 = acc3[fm][fn][r];
        AB[(size_t)m * Nd + n] = p1 / (1.f + __expf(-p1)) * p3;
      }
    }
}

// ---- per-head LN over DH=32 (no affine), emit bf16 hi/lo for MFMA build_M ----
__global__ __launch_bounds__(256) void qk_ln_split(const float* __restrict__ Q,
    const float* __restrict__ K, unsigned short* __restrict__ Qh,
    unsigned short* __restrict__ Ql, unsigned short* __restrict__ Kh,
    unsigned short* __restrict__ Kl) {
  const float* P = blockIdx.y ? K : Q;
  unsigned short* Dh = blockIdx.y ? Kh : Qh;
  unsigned short* Dl = blockIdx.y ? Kl : Ql;
  int t = threadIdx.x;
  int row = blockIdx.x * 8 + (t >> 5);
  int l = t & 31;
  const float* p = P + ((size_t)row << 5);
  float x = p[l];
  float s = x, q = x*x;
  #pragma unroll
  for (int off = 16; off; off >>= 1) { s += __shfl_xor(s, off, 32); q += __shfl_xor(q, off, 32); }
  float m = s * (1.f/32.f);
  float var = q * (1.f/32.f) - m*m;
  float inv = 1.f / sqrtf(var + 1e-5f);
  float y = (x - m) * inv;
  unsigned short hi = bf16r(y);
  Dh[((size_t)row << 5) + l] = hi;
  Dl[((size_t)row << 5) + l] = bf16r(y - bf16f(hi));
}

// ------- build M via MFMA QK^T; LDS-staged coalesced epilogue; int16 out (x256) -------
__global__ __launch_bounds__(256) void build_M(const unsigned short* __restrict__ Qh,
    const unsigned short* __restrict__ Ql, const unsigned short* __restrict__ Kh,
    const unsigned short* __restrict__ Kl, const float* __restrict__ wrel,
    const float* __restrict__ xres, const float* __restrict__ wdist,
    const float* __restrict__ ggate, short* __restrict__ Mq) {
  int jt = blockIdx.x, it = blockIdx.y, h = blockIdx.z;
  int t = threadIdx.x;
  __shared__ float S[64][65];
  __shared__ float xi[64][3], xj[64][3];
  if (t < 64) {
    int gi = (it << 6) + t, gj = (jt << 6) + t;
    xi[t][0] = xres[gi*3]; xi[t][1] = xres[gi*3+1]; xi[t][2] = xres[gi*3+2];
    xj[t][0] = xres[gj*3]; xj[t][1] = xres[gj*3+1]; xj[t][2] = xres[gj*3+2];
  }
  int wid = t >> 6, lane = t & 63;
  int wm = wid >> 1, wn = wid & 1;
  int lr = lane & 15, lk = lane >> 4;
  size_t hb = ((size_t)h << 10);
  short8 ah[2], al[2], bh[2], bl[2];
  #pragma unroll
  for (int fm = 0; fm < 2; ++fm) {
    size_t row = hb + (it << 6) + wm*32 + fm*16 + lr;
    ah[fm] = *(const short8*)(Qh + (row << 5) + lk*8);
    al[fm] = *(const short8*)(Ql + (row << 5) + lk*8);
  }
  #pragma unroll
  for (int fn = 0; fn < 2; ++fn) {
    size_t row = hb + (jt << 6) + wn*32 + fn*16 + lr;
    bh[fn] = *(const short8*)(Kh + (row << 5) + lk*8);
    bl[fn] = *(const short8*)(Kl + (row << 5) + lk*8);
  }
  f32x4 acc[2][2];
  #pragma unroll
  for (int i = 0; i < 2; ++i)
    #pragma unroll
    for (int j = 0; j < 2; ++j)
      #pragma unroll
      for (int r = 0; r < 4; ++r) acc[i][j][r] = 0.f;
  #pragma unroll
  for (int fm = 0; fm < 2; ++fm)
    #pragma unroll
    for (int fn = 0; fn < 2; ++fn) {
      acc[fm][fn] = mfma16(ah[fm], bh[fn], acc[fm][fn]);
      acc[fm][fn] = mfma16(al[fm], bh[fn], acc[fm][fn]);
      acc[fm][fn] = mfma16(ah[fm], bl[fn], acc[fm][fn]);
    }
  // stage accumulators into LDS (pad-65 => conflict-free)
  #pragma unroll
  for (int fm = 0; fm < 2; ++fm)
    #pragma unroll
    for (int fn = 0; fn < 2; ++fn)
      #pragma unroll
      for (int i = 0; i < 4; ++i)
        S[wm*32 + fm*16 + lk*4 + i][wn*32 + fn*16 + lr] = acc[fm][fn][i];
  __syncthreads();
  float inv_eps = 2.0f / (float)(1 << (h >> 2));
  float effw = ggate[h] * wdist[h];
  const float is32 = 0.17677669529663687f;
  int row16 = t >> 4;
  int col = (t & 15) << 2;
  #pragma unroll
  for (int rep = 0; rep < 4; ++rep) {
    int rl = row16 + (rep << 4);
    int rowg = (it << 6) + rl;
    int colg = (jt << 6) + col;
    size_t base = ((size_t)h << 20) + ((size_t)rowg << 10) + colg;
    float4 w4 = ld4(wrel + base);
    float xa0 = xi[rl][0], xa1 = xi[rl][1], xa2 = xi[rl][2];
    short o16[4];
    #pragma unroll
    for (int bq = 0; bq < 4; ++bq) {
      int cl = col + bq;
      float dx = xa0 - xj[cl][0], dy = xa1 - xj[cl][1], dz = xa2 - xj[cl][2];
      float d2 = dx*dx + dy*dy + dz*dz;
      float dist = sqrtf(fmaxf(d2, 1e-12f));
      float f = dist / (10.0f + dist);
      float wv = (bq==0)?w4.x:(bq==1)?w4.y:(bq==2)?w4.z:w4.w;
      float m = (S[rl][cl] * is32 - wv - effw * f) * inv_eps;
      o16[bq] = (short)__float2int_rn(fminf(fmaxf(m * 256.f, -32000.f), 32000.f));
    }
    short4 q4o; q4o.x = o16[0]; q4o.y = o16[1]; q4o.z = o16[2]; q4o.w = o16[3];
    *(short4*)(Mq + base) = q4o;
  }
}

// ------- Sinkhorn iteration: 16-row blocks, XCD-pinned head mapping -------
__global__ __launch_bounds__(256) void sink_iter8(const short* __restrict__ Mq,
    const float* __restrict__ lvb, const float* __restrict__ mu,
    float* __restrict__ lu_out, float* __restrict__ part) {
  __shared__ float lds[4][1024];
  __shared__ float logmu[16];
  int id = blockIdx.x;
  int h = (((id >> 3) & 1) << 3) | (id & 7);
  int bt = id >> 4;
  int t = threadIdx.x, w = t >> 6, lane = t & 63;
  float eps = 0.5f * (float)(1 << (h >> 2));
  float fac = 1.f / (1.f + eps);
  const float qs = 1.f / 256.f;
  int rowbase = bt << 4;
  if (t < 16) logmu[t] = __logf(fmaxf(mu[(h << 10) + rowbase + t], 1e-8f));
  const short* Mh = Mq + ((size_t)h << 20);
  int ib = rowbase + (w << 2);
  short8 qa[4], qb[4];
  #pragma unroll
  for (int k = 0; k < 4; ++k) {
    const short* row = Mh + ((size_t)(ib + k) << 10) + (lane << 3);
    qa[k] = *(const short8*)row;
    qb[k] = *(const short8*)(row + 512);
  }
  float4 lv4[2][2], env[2][2];
  #pragma unroll
  for (int c = 0; c < 2; ++c) {
    const float* lp = lvb + (h << 10) + (c << 9) + (lane << 3);
    lv4[c][0] = ld4(lp);
    lv4[c][1] = ld4(lp + 4);
    #pragma unroll
    for (int hv = 0; hv < 2; ++hv) {
      env[c][hv].x = __expf(-lv4[c][hv].x); env[c][hv].y = __expf(-lv4[c][hv].y);
      env[c][hv].z = __expf(-lv4[c][hv].z); env[c][hv].w = __expf(-lv4[c][hv].w);
    }
  }
  float4 colacc[2][2];
  #pragma unroll
  for (int c = 0; c < 2; ++c)
    #pragma unroll
    for (int hv = 0; hv < 2; ++hv) colacc[c][hv] = make_float4(0.f,0.f,0.f,0.f);
  #pragma unroll
  for (int k = 0; k < 4; ++k) {
    short8 q0 = qa[k], q1 = qb[k];
    float4 e[2][2];
    e[0][0].x = __expf((float)q0[0]*qs + lv4[0][0].x);
    e[0][0].y = __expf((float)q0[1]*qs + lv4[0][0].y);
    e[0][0].z = __expf((float)q0[2]*qs + lv4[0][0].z);
    e[0][0].w = __expf((float)q0[3]*qs + lv4[0][0].w);
    e[0][1].x = __expf((float)q0[4]*qs + lv4[0][1].x);
    e[0][1].y = __expf((float)q0[5]*qs + lv4[0][1].y);
    e[0][1].z = __expf((float)q0[6]*qs + lv4[0][1].z);
    e[0][1].w = __expf((float)q0[7]*qs + lv4[0][1].w);
    e[1][0].x = __expf((float)q1[0]*qs + lv4[1][0].x);
    e[1][0].y = __expf((float)q1[1]*qs + lv4[1][0].y);
    e[1][0].z = __expf((float)q1[2]*qs + lv4[1][0].z);
    e[1][0].w = __expf((float)q1[3]*qs + lv4[1][0].w);
    e[1][1].x = __expf((float)q1[4]*qs + lv4[1][1].x);
    e[1][1].y = __expf((float)q1[5]*qs + lv4[1][1].y);
    e[1][1].z = __expf((float)q1[6]*qs + lv4[1][1].z);
    e[1][1].w = __expf((float)q1[7]*qs + lv4[1][1].w);
    float racc = ((e[0][0].x + e[0][0].y) + (e[0][0].z + e[0][0].w))
               + ((e[0][1].x + e[0][1].y) + (e[0][1].z + e[0][1].w))
               + ((e[1][0].x + e[1][0].y) + (e[1][0].z + e[1][0].w))
               + ((e[1][1].x + e[1][1].y) + (e[1][1].z + e[1][1].w));
    #pragma unroll
    for (int off = 1; off < 64; off <<= 1) racc += __shfl_xor(racc, off);
    float lu = fac * (logmu[(w << 2) + k] - __logf(racc));
    if (lane == 0) lu_out[(h << 10) + ib + k] = lu;
    float s1 = __expf(lu);
    #pragma unroll
    for (int c = 0; c < 2; ++c)
      #pragma unroll
      for (int hv = 0; hv < 2; ++hv) {
        colacc[c][hv].x += s1 * (e[c][hv].x * env[c][hv].x);
        colacc[c][hv].y += s1 * (e[c][hv].y * env[c][hv].y);
        colacc[c][hv].z += s1 * (e[c][hv].z * env[c][hv].z);
        colacc[c][hv].w += s1 * (e[c][hv].w * env[c][hv].w);
      }
  }
  #pragma unroll
  for (int c = 0; c < 2; ++c) {
    st4(&lds[w][(c << 9) + (lane << 3)], colacc[c][0]);
    st4(&lds[w][(c << 9) + (lane << 3) + 4], colacc[c][1]);
  }
  __syncthreads();
  #pragma unroll
  for (int c = 0; c < 4; ++c) {
    int j = t + (c << 8);
    float v = (lds[0][j] + lds[1][j]) + (lds[2][j] + lds[3][j]);
    part[(((size_t)(h << 6) + bt) << 10) + j] = v;
  }
}

// ------- Sinkhorn col finalize: lv = fac*(log(nu) - log(sum of 64 partials)) -------
__global__ __launch_bounds__(256) void sink_fin(const float* __restrict__ part,
    const float* __restrict__ nu, float* __restrict__ lvb) {
  int cx = blockIdx.x, h = blockIdx.y;
  int t = threadIdx.x;
  float eps = 0.5f * (float)(1 << (h >> 2));
  float fac = 1.f / (1.f + eps);
  int j = (cx << 8) + t;
  float sum = 0.f;
  #pragma unroll 16
  for (int b = 0; b < 64; ++b)
    sum += part[(((size_t)(h << 6) + b) << 10) + j];
  float lv = fac * (__logf(fmaxf(nu[(h << 10) + j], 1e-8f)) - __logf(sum));
  lvb[(h << 10) + j] = lv;
}

// ---- build Bt[h][48][1024] bf16 = [V^T | x^T | ones | 0] for the attn MFMA ----
__global__ __launch_bounds__(256) void attn_prep(const float* __restrict__ V,
    const float* __restrict__ xres, unsigned short* __restrict__ Bt) {
  int jb = blockIdx.x, h = blockIdx.y;
  int t = threadIdx.x;
  #pragma unroll
  for (int rep = 0; rep < 12; ++rep) {
    int idx = t + (rep << 8);
    int jl = idx & 63, c = idx >> 6;
    int j = (jb << 6) + jl;
    float val;
    if (c < 32)      val = V[((((size_t)h << 10) + j) << 5) + c];
    else if (c < 35) val = xres[j * 3 + (c - 32)];
    else if (c == 35) val = 1.f;
    else              val = 0.f;
    Bt[(((size_t)h * 48 + c) << 10) + j] = bf16r(val);
  }
}

// ---- attn via MFMA: O[32 x 48] = e[32 x 1024] @ Bt^T; rows normalized by ones-col ----
__global__ __launch_bounds__(256) void attn_out_v6(const short* __restrict__ Mq,
    const unsigned short* __restrict__ Bt, const float* __restrict__ lu_g,
    const float* __restrict__ lv_g, const float* __restrict__ G,
    float* __restrict__ o_buf, float* __restrict__ xc) {
  __shared__ float lv_s[1024];
  __shared__ float lu_s[32];
  __shared__ float red[3][64][24];
  __shared__ float rs_s[32];
  int rb = blockIdx.x, h = blockIdx.y;
  int t = threadIdx.x, w = t >> 6, lane = t & 63;
  int lr = lane & 15, lk = lane >> 4;
  int rowbase = rb << 5;
  ((float4*)lv_s)[t] = ld4(lv_g + (h << 10) + (t << 2));
  if (t < 32) lu_s[t] = lu_g[(h << 10) + rowbase + t];
  __syncthreads();
  const float qs = 1.f / 256.f;
  float lu0 = lu_s[lr], lu1 = lu_s[16 + lr];
  const short* Mh = Mq + ((size_t)h << 20) + ((size_t)rowbase << 10);
  const unsigned short* Bh = Bt + (((size_t)h * 48) << 10);
  f32x4 acc[2][3];
  #pragma unroll
  for (int i = 0; i < 2; ++i)
    #pragma unroll
    for (int j = 0; j < 3; ++j)
      #pragma unroll
      for (int r = 0; r < 4; ++r) acc[i][j][r] = 0.f;
  for (int step = 0; step < 8; ++step) {
    int ks = (step << 2) | w;
    int j0 = (ks << 5) + (lk << 3);
    short8 m0 = *(const short8*)(Mh + ((size_t)lr << 10) + j0);
    short8 m1 = *(const short8*)(Mh + ((size_t)(16 + lr) << 10) + j0);
    short8 a0, a1;
    #pragma unroll
    for (int i = 0; i < 8; ++i) {
      float lvv = lv_s[j0 + i];
      a0[i] = (short)bf16r(__expf((float)m0[i] * qs + lu0 + lvv));
      a1[i] = (short)bf16r(__expf((float)m1[i] * qs + lu1 + lvv));
    }
    short8 b0 = *(const short8*)(Bh + ((size_t)lr << 10) + j0);
    short8 b1 = *(const short8*)(Bh + ((size_t)(16 + lr) << 10) + j0);
    short8 b2 = *(const short8*)(Bh + ((size_t)(32 + lr) << 10) + j0);
    acc[0][0] = mfma16(a0, b0, acc[0][0]);
    acc[0][1] = mfma16(a0, b1, acc[0][1]);
    acc[0][2] = mfma16(a0, b2, acc[0][2]);
    acc[1][0] = mfma16(a1, b0, acc[1][0]);
    acc[1][1] = mfma16(a1, b1, acc[1][1]);
    acc[1][2] = mfma16(a1, b2, acc[1][2]);
  }
  if (w) {
    #pragma unroll
    for (int fm = 0; fm < 2; ++fm)
      #pragma unroll
      for (int fn = 0; fn < 3; ++fn)
        #pragma unroll
        for (int i = 0; i < 4; ++i)
          red[w - 1][lane][(fm * 3 + fn) * 4 + i] = acc[fm][fn][i];
  }
  __syncthreads();
  if (w == 0) {
    #pragma unroll
    for (int fm = 0; fm < 2; ++fm)
      #pragma unroll
      for (int fn = 0; fn < 3; ++fn)
        #pragma unroll
        for (int i = 0; i < 4; ++i)
          acc[fm][fn][i] += red[0][lane][(fm*3+fn)*4+i] + red[1][lane][(fm*3+fn)*4+i]
                          + red[2][lane][(fm*3+fn)*4+i];
    if (lr == 3) {
      #pragma unroll
      for (int fm = 0; fm < 2; ++fm)
        #pragma unroll
        for (int i = 0; i < 4; ++i)
          rs_s[fm*16 + lk*4 + i] = acc[fm][2][i];
    }
    #pragma unroll
    for (int fm = 0; fm < 2; ++fm)
      #pragma unroll
      for (int fn = 0; fn < 2; ++fn)
        #pragma unroll
        for (int i = 0; i < 4; ++i) {
          int rl = fm*16 + lk*4 + i;
          int row = rowbase + rl;
          int col = fn*16 + lr;
          float inv = 1.f / (rs_s[rl] + 1e-8f);
          size_t ga = ((size_t)row << 9) + h*32 + col;
          float g = G[ga];
          o_buf[ga] = acc[fm][fn][i] * inv / (1.f + __expf(-g));
        }
    if (lr < 3) {
      #pragma unroll
      for (int fm = 0; fm < 2; ++fm)
        #pragma unroll
        for (int i = 0; i < 4; ++i) {
          int rl = fm*16 + lk*4 + i;
          int row = rowbase + rl;
          xc[((size_t)((h << 10) + row)) * 3 + lr] = acc[fm][2][i] / (rs_s[rl] + 1e-8f);
        }
    }
  }
}

// ---------------- x_res update ----------------
__global__ void x_update(const float* __restrict__ xres, const float* __restrict__ xc,
    const float* __restrict__ gamma, float* __restrict__ xout) {
  int idx = blockIdx.x * 256 + threadIdx.x;
  if (idx >= 3072) return;
  float x = xres[idx];
  float s = x;
  #pragma unroll
  for (int hh = 0; hh < 16; ++hh) s += gamma[hh] * (x - xc[(size_t)hh * 3072 + idx]);
  xout[idx] = s;
}

// ---------------- o = a + b + c ----------------
__global__ __launch_bounds__(256) void add3(const float* __restrict__ a,
    const float* __restrict__ b, const float* __restrict__ c, float* __restrict__ o) {
  int i = (blockIdx.x * 256 + threadIdx.x) << 2;
  float4 va = ld4(a + i), vb = ld4(b + i), vc = ld4(c + i);
  st4(o + i, make_float4(va.x+vb.x+vc.x, va.y+vb.y+vc.y, va.z+vb.z+vc.z, va.w+vb.w+vc.w));
}

extern "C" void kernel_launch(void* const* d_in, const int* in_sizes, int n_in,
                              void* d_out, int out_size, void* d_ws, size_t ws_size,
                              hipStream_t stream) {
  const float* h_in    = (const float*)d_in[0];
  const float* x_res   = (const float*)d_in[1];
  const float* mu      = (const float*)d_in[2];
  const float* nu      = (const float*)d_in[3];
  const float* lv_prev = (const float*)d_in[5];
  const float* wrel    = (const float*)d_in[6];
  const float* wdist   = (const float*)d_in[7];
  const float* ggate   = (const float*)d_in[9];
  const float* lnaw    = (const float*)d_in[10];
  const float* lnab    = (const float*)d_in[11];
  const float* Wq      = (const float*)d_in[12];
  const float* Wk      = (const float*)d_in[13];
  const float* Wv      = (const float*)d_in[14];
  const float* Wg      = (const float*)d_in[15];
  const float* Wo      = (const float*)d_in[16];
  const float* gamma   = (const float*)d_in[17];
  const float* lnfw    = (const float*)d_in[18];
  const float* lnfb    = (const float*)d_in[19];
  const float* W1      = (const float*)d_in[20];
  const float* W3      = (const float*)d_in[21];
  const float* W2      = (const float*)d_in[22];

  float* out = (float*)d_out;
  float* OUT_H  = out;
  float* OUT_X  = out + 524288;
  float* OUT_LU = out + 527360;
  float* OUT_LV = out + 543744;   // working lv buffer

  if (ws_size < (size_t)19988480 * sizeof(float)) return;
  float* ws   = (float*)d_ws;
  float* Qb   = ws;                    // 524288 (H,N,32) f32
  float* Kb   = ws + 524288;           // 524288
  float* Vb   = ws + 1048576;          // 524288
  float* Gb   = ws + 1572864;          // 524288 (N,D) f32
  float* Mb   = ws + 2097152;          // Mq int16 = 16777216 shorts = first 8388608 floats
  float* part = ws + 18874368;         // 1048576 (H,64,N) col partials
  float* xcb  = ws + 19922944;         // 49152
  short* Mq   = (short*)Mb;
  // Phase-A overlays inside Mb (dead before build_M writes Mq):
  float* h_n = Mb;                                        // 1024x512 f32
  unsigned short* WqT = (unsigned short*)(Mb + 524288);
  unsigned short* WkT = (unsigned short*)(Mb + 786432);
  unsigned short* WvT = (unsigned short*)(Mb + 1048576);
  unsigned short* WgT = (unsigned short*)(Mb + 1310720);
  // bf16 hi/lo LN'd Q/K — beyond Mq's 8388608-float extent:
  unsigned short* Qhh = (unsigned short*)(Mb + 8388608);  // 262144 floats each
  unsigned short* Qll = (unsigned short*)(Mb + 8650752);
  unsigned short* Khh = (unsigned short*)(Mb + 8912896);
  unsigned short* Kll = (unsigned short*)(Mb + 9175040);  // ends 9437184
  // Bt overlays the (dead after build_M) Qhh region: 786432 shorts = 393216 floats
  unsigned short* Bt = (unsigned short*)(Mb + 8388608);   // ends 8781824
  // Phase-B overlays inside Mb (Mq dead after attn_out_v6):
  float* ABb = Mb + 4194304;                               // written after attn
  unsigned short* W1T = (unsigned short*)(Mb + 0);         // 2048x512 hi+lo = 1048576 floats
  unsigned short* W3T = (unsigned short*)(Mb + 1048576);
  unsigned short* W2T = (unsigned short*)(Mb + 2097152);   // 512x2048 hi+lo = 1048576 floats
  unsigned short* WoT = (unsigned short*)(Mb + 3145728);   // 512x512 hi+lo = 262144 floats
  float* Pa = Mb + 6291456;                                // 524288 f32
  float* Pb = Mb + 6815744;                                // 524288 f32
  // Other reuse:
  float* o_buf = part;                 // 1024x512 f32 (part dead after sink)
  float* h2  = Qb;
  float* ffb = Kb;

  // --- attention input projections (split-precision bf16 MFMA) ---
  ln_rows<<<NTOK, 256, 0, stream>>>(h_in, lnaw, lnab, h_n);
  {
    C4 c = { Wq, Wk, Wv, Wg, WqT, WkT, WvT, WgT };
    convT<<<dim3(8, 8, 4), 256, 0, stream>>>(c, 512, 512);
  }
  {
    P4 p = { WqT, WkT, WvT, WgT, Qb, Kb, Vb, Gb };
    gemm_mfma<0><<<dim3(8, 16, 4), 256, 0, stream>>>(h_n, p, 512, 512, 0);
  }
  qk_ln_split<<<dim3(2048, 2), 256, 0, stream>>>(Qb, Kb, Qhh, Qll, Khh, Kll);
  build_M<<<dim3(16, 16, 16), 256, 0, stream>>>(Qhh, Qll, Khh, Kll, wrel, x_res,
                                                wdist, ggate, Mq);
  attn_prep<<<dim3(16, 16), 256, 0, stream>>>(Vb, x_res, Bt);
  hipMemcpyAsync(OUT_LV, lv_prev, 16384 * sizeof(float), hipMemcpyDeviceToDevice, stream);
  for (int it = 0; it < 20; ++it) {
    sink_iter8<<<1024, 256, 0, stream>>>(Mq, OUT_LV, mu, OUT_LU, part);
    sink_fin<<<dim3(4, 16), 256, 0, stream>>>(part, nu, OUT_LV);
  }
  attn_out_v6<<<dim3(32, 16), 256, 0, stream>>>(Mq, Bt, OUT_LU, OUT_LV, Gb, o_buf, xcb);
  x_update<<<12, 256, 0, stream>>>(x_res, xcb, gamma, OUT_X);

  // --- output projection + FFN (weight convTs overwrite Mq region, now dead) ---
  {
    C4 c = { Wo, nullptr, nullptr, nullptr, WoT, nullptr, nullptr, nullptr };
    convT<<<dim3(8, 8, 1), 256, 0, stream>>>(c, 512, 512);
  }
  {
    C4 c = { W1, W3, nullptr, nullptr, W1T, W3T, nullptr, nullptr };
    convT<<<dim3(32, 8, 2), 256, 0, stream>>>(c, 512, 2048);
  }
  {
    C4 c = { W2, nullptr, nullptr, nullptr, W2T, nullptr, nullptr, nullptr };
    convT<<<dim3(8, 32, 1), 256, 0, stream>>>(c, 2048, 512);
  }
  {
    P4 p = { WoT, WoT, nullptr, nullptr, Pa, Pb, nullptr, nullptr };
    gemm_mfma<1><<<dim3(8, 16, 2), 256, 0, stream>>>(o_buf, p, 512, 512, 256);
  }
  ln_rows3<<<NTOK, 256, 0, stream>>>(Pa, Pb, h_in, lnfw, lnfb, h2, ffb);
  gemm_w13<<<dim3(32, 16), 256, 0, stream>>>(ffb, W1T, W3T, ABb);
  {
    P4 p = { W2T, W2T, nullptr, nullptr, Pa, Pb, nullptr, nullptr };
    gemm_mfma<1><<<dim3(8, 16, 2), 256, 0, stream>>>(ABb, p, 2048, 512, 1024);
  }
  add3<<<512, 256, 0, stream>>>(Pa, Pb, h2, OUT_H);
}

// Round 16
// 406.021 us; speedup vs baseline: 1.0020x; 1.0020x over previous
//
#include <hip/hip_runtime.h>
#include <math.h>

#define NTOK 1024
#define DDIM 512

using short8 = __attribute__((ext_vector_type(8))) short;
using f32x4  = __attribute__((ext_vector_type(4))) float;

__device__ __forceinline__ float4 ld4(const float* p){ return *(const float4*)p; }
__device__ __forceinline__ void st4(float* p, float4 v){ *(float4*)p = v; }
__device__ __forceinline__ unsigned short bf16r(float x) {
  unsigned int u = __float_as_uint(x);
  u += 0x7fffu + ((u >> 16) & 1u);
  return (unsigned short)(u >> 16);
}
__device__ __forceinline__ float bf16f(unsigned short h) {
  return __uint_as_float(((unsigned int)h) << 16);
}
__device__ __forceinline__ f32x4 mfma16(short8 a, short8 b, f32x4 c) {
  return __builtin_amdgcn_mfma_f32_16x16x32_bf16(a, b, c, 0, 0, 0);
}

// ---------------- LayerNorm over D=512 with affine, fp32 out ----------------
__global__ __launch_bounds__(256) void ln_rows(const float* __restrict__ x,
    const float* __restrict__ w, const float* __restrict__ b, float* __restrict__ y) {
  int row = blockIdx.x, t = threadIdx.x;
  const float* xr = x + ((size_t)row << 9);
  float v0 = xr[t], v1 = xr[t + 256];
  float s = v0 + v1, q = v0*v0 + v1*v1;
  #pragma unroll
  for (int off = 1; off < 64; off <<= 1) { s += __shfl_xor(s, off); q += __shfl_xor(q, off); }
  __shared__ float ls[4], lq[4], mb[2];
  int wv = t >> 6;
  if ((t & 63) == 0) { ls[wv] = s; lq[wv] = q; }
  __syncthreads();
  if (t == 0) {
    float S = ls[0]+ls[1]+ls[2]+ls[3];
    float Q = lq[0]+lq[1]+lq[2]+lq[3];
    float m = S * (1.f/512.f);
    float var = Q * (1.f/512.f) - m*m;
    mb[0] = m; mb[1] = 1.f / sqrtf(var + 1e-5f);
  }
  __syncthreads();
  float m = mb[0], inv = mb[1];
  float* yr = y + ((size_t)row << 9);
  yr[t]       = (v0 - m) * inv * w[t] + b[t];
  yr[t + 256] = (v1 - m) * inv * w[t + 256] + b[t + 256];
}

// ---- fused: v = pa+pb+hin; write v (residual) and LN(v) ----
__global__ __launch_bounds__(256) void ln_rows3(const float* __restrict__ pa,
    const float* __restrict__ pb, const float* __restrict__ hi,
    const float* __restrict__ w, const float* __restrict__ b,
    float* __restrict__ hsum, float* __restrict__ y) {
  int row = blockIdx.x, t = threadIdx.x;
  size_t base = ((size_t)row << 9);
  float v0 = pa[base + t] + pb[base + t] + hi[base + t];
  float v1 = pa[base + t + 256] + pb[base + t + 256] + hi[base + t + 256];
  float s = v0 + v1, q = v0*v0 + v1*v1;
  #pragma unroll
  for (int off = 1; off < 64; off <<= 1) { s += __shfl_xor(s, off); q += __shfl_xor(q, off); }
  __shared__ float ls[4], lq[4], mb[2];
  int wv = t >> 6;
  if ((t & 63) == 0) { ls[wv] = s; lq[wv] = q; }
  __syncthreads();
  if (t == 0) {
    float S = ls[0]+ls[1]+ls[2]+ls[3];
    float Q = lq[0]+lq[1]+lq[2]+lq[3];
    float m = S * (1.f/512.f);
    float var = Q * (1.f/512.f) - m*m;
    mb[0] = m; mb[1] = 1.f / sqrtf(var + 1e-5f);
  }
  __syncthreads();
  float m = mb[0], inv = mb[1];
  hsum[base + t] = v0;
  hsum[base + t + 256] = v1;
  y[base + t]       = (v0 - m) * inv * w[t] + b[t];
  y[base + t + 256] = (v1 - m) * inv * w[t + 256] + b[t + 256];
}

// ------- convert + transpose + hi/lo split (multi-weight via blockIdx.z) -------
struct C4 {
  const float *S0, *S1, *S2, *S3;
  unsigned short *D0, *D1, *D2, *D3;
};
__global__ __launch_bounds__(256) void convT(C4 p, int K, int N) {
  __shared__ unsigned short Th[64][68];
  __shared__ unsigned short Tl[64][68];
  int z = blockIdx.z;
  const float* src = (z==0)?p.S0:(z==1)?p.S1:(z==2)?p.S2:p.S3;
  unsigned short* dst = (z==0)?p.D0:(z==1)?p.D1:(z==2)?p.D2:p.D3;
  int nt = blockIdx.x << 6, kt = blockIdx.y << 6;
  int t = threadIdx.x;
  int r = t >> 4, c4 = (t & 15) << 2;
  #pragma unroll
  for (int pp = 0; pp < 4; ++pp) {
    int kk = r + (pp << 4);
    float4 v = ld4(src + (size_t)(kt + kk) * N + nt + c4);
    float vv[4] = {v.x, v.y, v.z, v.w};
    #pragma unroll
    for (int i = 0; i < 4; ++i) {
      unsigned short h = bf16r(vv[i]);
      Th[c4 + i][kk] = h;
      Tl[c4 + i][kk] = bf16r(vv[i] - bf16f(h));
    }
  }
  __syncthreads();
  size_t loff = (size_t)N * K;
  #pragma unroll
  for (int pp = 0; pp < 4; ++pp) {
    int nn = r + (pp << 4);
    ushort4 oh, ol;
    oh.x = Th[nn][c4]; oh.y = Th[nn][c4+1]; oh.z = Th[nn][c4+2]; oh.w = Th[nn][c4+3];
    ol.x = Tl[nn][c4]; ol.y = Tl[nn][c4+1]; ol.z = Tl[nn][c4+2]; ol.w = Tl[nn][c4+3];
    *(ushort4*)(dst + (size_t)(nt + nn) * K + kt + c4) = oh;
    *(ushort4*)(dst + loff + (size_t)(nt + nn) * K + kt + c4) = ol;
  }
}

// ---------------- split-precision bf16 MFMA GEMM ----------------
struct P4 {
  const unsigned short *W0, *W1, *W2, *W3;
  float *C0, *C1, *C2, *C3;
};
template<int MODE>
__global__ __launch_bounds__(256) void gemm_mfma(const float* __restrict__ A,
    P4 p, int Kd, int Nd, int kwin) {
  __shared__ unsigned short Ash[64][72];
  __shared__ unsigned short Asl[64][72];
  __shared__ unsigned short Bsh[64][72];
  __shared__ unsigned short Bsl[64][72];
  int t = threadIdx.x;
  int z = blockIdx.z;
  const unsigned short* W = (z==0)?p.W0:(z==1)?p.W1:(z==2)?p.W2:p.W3;
  float* C = (z==0)?p.C0:(z==1)?p.C1:(z==2)?p.C2:p.C3;
  const unsigned short* Wl = W + (size_t)Nd * Kd;
  int bm = blockIdx.y << 6, bn = blockIdx.x << 6;
  int wid = t >> 6, lane = t & 63;
  int wm = wid >> 1, wn = wid & 1;
  int lr = lane & 15, lk = lane >> 4;
  int r0 = t >> 3, ks = (t & 7) << 3;
  int kbeg = kwin ? z * kwin : 0;
  int kend = kwin ? kbeg + kwin : Kd;
  f32x4 acc[2][2];
  #pragma unroll
  for (int i = 0; i < 2; ++i)
    #pragma unroll
    for (int j = 0; j < 2; ++j)
      #pragma unroll
      for (int r = 0; r < 4; ++r) acc[i][j][r] = 0.f;
  for (int k0 = kbeg; k0 < kend; k0 += 64) {
    float4 a00 = ld4(A + (size_t)(bm + r0) * Kd + k0 + ks);
    float4 a01 = ld4(A + (size_t)(bm + r0) * Kd + k0 + ks + 4);
    float4 a10 = ld4(A + (size_t)(bm + r0 + 32) * Kd + k0 + ks);
    float4 a11 = ld4(A + (size_t)(bm + r0 + 32) * Kd + k0 + ks + 4);
    uint4 b0h = *(const uint4*)(W  + (size_t)(bn + r0) * Kd + k0 + ks);
    uint4 b1h = *(const uint4*)(W  + (size_t)(bn + r0 + 32) * Kd + k0 + ks);
    uint4 b0l = *(const uint4*)(Wl + (size_t)(bn + r0) * Kd + k0 + ks);
    uint4 b1l = *(const uint4*)(Wl + (size_t)(bn + r0 + 32) * Kd + k0 + ks);
    __syncthreads();
    {
      float va[8] = {a00.x,a00.y,a00.z,a00.w,a01.x,a01.y,a01.z,a01.w};
      short8 h8, l8;
      #pragma unroll
      for (int i = 0; i < 8; ++i) {
        unsigned short h = bf16r(va[i]);
        h8[i] = (short)h; l8[i] = (short)bf16r(va[i] - bf16f(h));
      }
      *(short8*)&Ash[r0][ks] = h8;
      *(short8*)&Asl[r0][ks] = l8;
    }
    {
      float va[8] = {a10.x,a10.y,a10.z,a10.w,a11.x,a11.y,a11.z,a11.w};
      short8 h8, l8;
      #pragma unroll
      for (int i = 0; i < 8; ++i) {
        unsigned short h = bf16r(va[i]);
        h8[i] = (short)h; l8[i] = (short)bf16r(va[i] - bf16f(h));
      }
      *(short8*)&Ash[r0 + 32][ks] = h8;
      *(short8*)&Asl[r0 + 32][ks] = l8;
    }
    *(uint4*)&Bsh[r0][ks] = b0h;
    *(uint4*)&Bsh[r0 + 32][ks] = b1h;
    *(uint4*)&Bsl[r0][ks] = b0l;
    *(uint4*)&Bsl[r0 + 32][ks] = b1l;
    __syncthreads();
    #pragma unroll
    for (int s = 0; s < 2; ++s) {
      short8 ah0 = *(const short8*)&Ash[wm*32 + lr][s*32 + lk*8];
      short8 ah1 = *(const short8*)&Ash[wm*32 + 16 + lr][s*32 + lk*8];
      short8 al0 = *(const short8*)&Asl[wm*32 + lr][s*32 + lk*8];
      short8 al1 = *(const short8*)&Asl[wm*32 + 16 + lr][s*32 + lk*8];
      short8 bh0 = *(const short8*)&Bsh[wn*32 + lr][s*32 + lk*8];
      short8 bh1 = *(const short8*)&Bsh[wn*32 + 16 + lr][s*32 + lk*8];
      short8 bl0 = *(const short8*)&Bsl[wn*32 + lr][s*32 + lk*8];
      short8 bl1 = *(const short8*)&Bsl[wn*32 + 16 + lr][s*32 + lk*8];
      acc[0][0] = mfma16(ah0, bh0, acc[0][0]);
      acc[0][1] = mfma16(ah0, bh1, acc[0][1]);
      acc[1][0] = mfma16(ah1, bh0, acc[1][0]);
      acc[1][1] = mfma16(ah1, bh1, acc[1][1]);
      acc[0][0] = mfma16(al0, bh0, acc[0][0]);
      acc[0][1] = mfma16(al0, bh1, acc[0][1]);
      acc[1][0] = mfma16(al1, bh0, acc[1][0]);
      acc[1][1] = mfma16(al1, bh1, acc[1][1]);
      acc[0][0] = mfma16(ah0, bl0, acc[0][0]);
      acc[0][1] = mfma16(ah0, bl1, acc[0][1]);
      acc[1][0] = mfma16(ah1, bl0, acc[1][0]);
      acc[1][1] = mfma16(ah1, bl1, acc[1][1]);
    }
  }
  #pragma unroll
  for (int fm = 0; fm < 2; ++fm)
    #pragma unroll
    for (int fn = 0; fn < 2; ++fn) {
      int n = bn + wn*32 + fn*16 + lr;
      #pragma unroll
      for (int r = 0; r < 4; ++r) {
        int m = bm + wm*32 + fm*16 + lk*4 + r;
        float v = acc[fm][fn][r];
        if (MODE == 0) {
          if (z < 3) C[(((size_t)(n >> 5) << 10) + m) * 32 + (n & 31)] = v;
          else       C[(size_t)m * Nd + n] = v;
        } else {
          C[(size_t)m * Nd + n] = v;
        }
      }
    }
}

// ---- dual-weight W1/W3 GEMM with fused silu(p1)*p3 epilogue (K=512, N=2048) ----
__global__ __launch_bounds__(256) void gemm_w13(const float* __restrict__ A,
    const unsigned short* __restrict__ W1T, const unsigned short* __restrict__ W3T,
    float* __restrict__ AB) {
  __shared__ unsigned short Ash[64][72];
  __shared__ unsigned short Asl[64][72];
  __shared__ unsigned short B1h[64][72];
  __shared__ unsigned short B1l[64][72];
  __shared__ unsigned short B3h[64][72];
  __shared__ unsigned short B3l[64][72];
  const int Kd = 512, Nd = 2048;
  int t = threadIdx.x;
  const unsigned short* W1l = W1T + (size_t)Nd * Kd;
  const unsigned short* W3l = W3T + (size_t)Nd * Kd;
  int bm = blockIdx.y << 6, bn = blockIdx.x << 6;
  int wid = t >> 6, lane = t & 63;
  int wm = wid >> 1, wn = wid & 1;
  int lr = lane & 15, lk = lane >> 4;
  int r0 = t >> 3, ks = (t & 7) << 3;
  f32x4 acc1[2][2], acc3[2][2];
  #pragma unroll
  for (int i = 0; i < 2; ++i)
    #pragma unroll
    for (int j = 0; j < 2; ++j)
      #pragma unroll
      for (int r = 0; r < 4; ++r) { acc1[i][j][r] = 0.f; acc3[i][j][r] = 0.f; }
  for (int k0 = 0; k0 < Kd; k0 += 64) {
    float4 a00 = ld4(A + (size_t)(bm + r0) * Kd + k0 + ks);
    float4 a01 = ld4(A + (size_t)(bm + r0) * Kd + k0 + ks + 4);
    float4 a10 = ld4(A + (size_t)(bm + r0 + 32) * Kd + k0 + ks);
    float4 a11 = ld4(A + (size_t)(bm + r0 + 32) * Kd + k0 + ks + 4);
    uint4 c0h = *(const uint4*)(W1T + (size_t)(bn + r0) * Kd + k0 + ks);
    uint4 c1h = *(const uint4*)(W1T + (size_t)(bn + r0 + 32) * Kd + k0 + ks);
    uint4 c0l = *(const uint4*)(W1l + (size_t)(bn + r0) * Kd + k0 + ks);
    uint4 c1l = *(const uint4*)(W1l + (size_t)(bn + r0 + 32) * Kd + k0 + ks);
    uint4 d0h = *(const uint4*)(W3T + (size_t)(bn + r0) * Kd + k0 + ks);
    uint4 d1h = *(const uint4*)(W3T + (size_t)(bn + r0 + 32) * Kd + k0 + ks);
    uint4 d0l = *(const uint4*)(W3l + (size_t)(bn + r0) * Kd + k0 + ks);
    uint4 d1l = *(const uint4*)(W3l + (size_t)(bn + r0 + 32) * Kd + k0 + ks);
    __syncthreads();
    {
      float va[8] = {a00.x,a00.y,a00.z,a00.w,a01.x,a01.y,a01.z,a01.w};
      short8 h8, l8;
      #pragma unroll
      for (int i = 0; i < 8; ++i) {
        unsigned short h = bf16r(va[i]);
        h8[i] = (short)h; l8[i] = (short)bf16r(va[i] - bf16f(h));
      }
      *(short8*)&Ash[r0][ks] = h8;
      *(short8*)&Asl[r0][ks] = l8;
    }
    {
      float va[8] = {a10.x,a10.y,a10.z,a10.w,a11.x,a11.y,a11.z,a11.w};
      short8 h8, l8;
      #pragma unroll
      for (int i = 0; i < 8; ++i) {
        unsigned short h = bf16r(va[i]);
        h8[i] = (short)h; l8[i] = (short)bf16r(va[i] - bf16f(h));
      }
      *(short8*)&Ash[r0 + 32][ks] = h8;
      *(short8*)&Asl[r0 + 32][ks] = l8;
    }
    *(uint4*)&B1h[r0][ks] = c0h;  *(uint4*)&B1h[r0 + 32][ks] = c1h;
    *(uint4*)&B1l[r0][ks] = c0l;  *(uint4*)&B1l[r0 + 32][ks] = c1l;
    *(uint4*)&B3h[r0][ks] = d0h;  *(uint4*)&B3h[r0 + 32][ks] = d1h;
    *(uint4*)&B3l[r0][ks] = d0l;  *(uint4*)&B3l[r0 + 32][ks] = d1l;
    __syncthreads();
    #pragma unroll
    for (int s = 0; s < 2; ++s) {
      short8 ah0 = *(const short8*)&Ash[wm*32 + lr][s*32 + lk*8];
      short8 ah1 = *(const short8*)&Ash[wm*32 + 16 + lr][s*32 + lk*8];
      short8 al0 = *(const short8*)&Asl[wm*32 + lr][s*32 + lk*8];
      short8 al1 = *(const short8*)&Asl[wm*32 + 16 + lr][s*32 + lk*8];
      short8 p0h = *(const short8*)&B1h[wn*32 + lr][s*32 + lk*8];
      short8 p1h = *(const short8*)&B1h[wn*32 + 16 + lr][s*32 + lk*8];
      short8 p0l = *(const short8*)&B1l[wn*32 + lr][s*32 + lk*8];
      short8 p1l = *(const short8*)&B1l[wn*32 + 16 + lr][s*32 + lk*8];
      acc1[0][0] = mfma16(ah0, p0h, acc1[0][0]);
      acc1[0][1] = mfma16(ah0, p1h, acc1[0][1]);
      acc1[1][0] = mfma16(ah1, p0h, acc1[1][0]);
      acc1[1][1] = mfma16(ah1, p1h, acc1[1][1]);
      acc1[0][0] = mfma16(al0, p0h, acc1[0][0]);
      acc1[0][1] = mfma16(al0, p1h, acc1[0][1]);
      acc1[1][0] = mfma16(al1, p0h, acc1[1][0]);
      acc1[1][1] = mfma16(al1, p1h, acc1[1][1]);
      acc1[0][0] = mfma16(ah0, p0l, acc1[0][0]);
      acc1[0][1] = mfma16(ah0, p1l, acc1[0][1]);
      acc1[1][0] = mfma16(ah1, p0l, acc1[1][0]);
      acc1[1][1] = mfma16(ah1, p1l, acc1[1][1]);
      short8 q0h = *(const short8*)&B3h[wn*32 + lr][s*32 + lk*8];
      short8 q1h = *(const short8*)&B3h[wn*32 + 16 + lr][s*32 + lk*8];
      short8 q0l = *(const short8*)&B3l[wn*32 + lr][s*32 + lk*8];
      short8 q1l = *(const short8*)&B3l[wn*32 + 16 + lr][s*32 + lk*8];
      acc3[0][0] = mfma16(ah0, q0h, acc3[0][0]);
      acc3[0][1] = mfma16(ah0, q1h, acc3[0][1]);
      acc3[1][0] = mfma16(ah1, q0h, acc3[1][0]);
      acc3[1][1] = mfma16(ah1, q1h, acc3[1][1]);
      acc3[0][0] = mfma16(al0, q0h, acc3[0][0]);
      acc3[0][1] = mfma16(al0, q1h, acc3[0][1]);
      acc3[1][0] = mfma16(al1, q0h, acc3[1][0]);
      acc3[1][1] = mfma16(al1, q1h, acc3[1][1]);
      acc3[0][0] = mfma16(ah0, q0l, acc3[0][0]);
      acc3[0][1] = mfma16(ah0, q1l, acc3[0][1]);
      acc3[1][0] = mfma16(ah1, q0l, acc3[1][0]);
      acc3[1][1] = mfma16(ah1, q1l, acc3[1][1]);
    }
  }
  #pragma unroll
  for (int fm = 0; fm < 2; ++fm)
    #pragma unroll
    for (int fn = 0; fn < 2; ++fn) {
      int n = bn + wn*32 + fn*16 + lr;
      #pragma unroll
      for (int r = 0; r < 4; ++r) {
        int m = bm + wm*32 + fm*16 + lk*4 + r;
        float p1 = acc1[fm][fn][r];
        float p3 = acc3[fm][fn][r];
        AB[(size_t)m * Nd + n] = p1 / (1.f + __expf(-p1)) * p3;
      }
    }
}

// ---- per-head LN over DH=32 (no affine), emit bf16 hi/lo for MFMA build_M ----
__global__ __launch_bounds__(256) void qk_ln_split(const float* __restrict__ Q,
    const float* __restrict__ K, unsigned short* __restrict__ Qh,
    unsigned short* __restrict__ Ql, unsigned short* __restrict__ Kh,
    unsigned short* __restrict__ Kl) {
  const float* P = blockIdx.y ? K : Q;
  unsigned short* Dh = blockIdx.y ? Kh : Qh;
  unsigned short* Dl = blockIdx.y ? Kl : Ql;
  int t = threadIdx.x;
  int row = blockIdx.x * 8 + (t >> 5);
  int l = t & 31;
  const float* p = P + ((size_t)row << 5);
  float x = p[l];
  float s = x, q = x*x;
  #pragma unroll
  for (int off = 16; off; off >>= 1) { s += __shfl_xor(s, off, 32); q += __shfl_xor(q, off, 32); }
  float m = s * (1.f/32.f);
  float var = q * (1.f/32.f) - m*m;
  float inv = 1.f / sqrtf(var + 1e-5f);
  float y = (x - m) * inv;
  unsigned short hi = bf16r(y);
  Dh[((size_t)row << 5) + l] = hi;
  Dl[((size_t)row << 5) + l] = bf16r(y - bf16f(hi));
}

// ------- build M via MFMA QK^T; LDS-staged coalesced epilogue; int16 out (x256) -------
__global__ __launch_bounds__(256) void build_M(const unsigned short* __restrict__ Qh,
    const unsigned short* __restrict__ Ql, const unsigned short* __restrict__ Kh,
    const unsigned short* __restrict__ Kl, const float* __restrict__ wrel,
    const float* __restrict__ xres, const float* __restrict__ wdist,
    const float* __restrict__ ggate, short* __restrict__ Mq) {
  int jt = blockIdx.x, it = blockIdx.y, h = blockIdx.z;
  int t = threadIdx.x;
  __shared__ float S[64][65];
  __shared__ float xi[64][3], xj[64][3];
  if (t < 64) {
    int gi = (it << 6) + t, gj = (jt << 6) + t;
    xi[t][0] = xres[gi*3]; xi[t][1] = xres[gi*3+1]; xi[t][2] = xres[gi*3+2];
    xj[t][0] = xres[gj*3]; xj[t][1] = xres[gj*3+1]; xj[t][2] = xres[gj*3+2];
  }
  int wid = t >> 6, lane = t & 63;
  int wm = wid >> 1, wn = wid & 1;
  int lr = lane & 15, lk = lane >> 4;
  size_t hb = ((size_t)h << 10);
  short8 ah[2], al[2], bh[2], bl[2];
  #pragma unroll
  for (int fm = 0; fm < 2; ++fm) {
    size_t row = hb + (it << 6) + wm*32 + fm*16 + lr;
    ah[fm] = *(const short8*)(Qh + (row << 5) + lk*8);
    al[fm] = *(const short8*)(Ql + (row << 5) + lk*8);
  }
  #pragma unroll
  for (int fn = 0; fn < 2; ++fn) {
    size_t row = hb + (jt << 6) + wn*32 + fn*16 + lr;
    bh[fn] = *(const short8*)(Kh + (row << 5) + lk*8);
    bl[fn] = *(const short8*)(Kl + (row << 5) + lk*8);
  }
  f32x4 acc[2][2];
  #pragma unroll
  for (int i = 0; i < 2; ++i)
    #pragma unroll
    for (int j = 0; j < 2; ++j)
      #pragma unroll
      for (int r = 0; r < 4; ++r) acc[i][j][r] = 0.f;
  #pragma unroll
  for (int fm = 0; fm < 2; ++fm)
    #pragma unroll
    for (int fn = 0; fn < 2; ++fn) {
      acc[fm][fn] = mfma16(ah[fm], bh[fn], acc[fm][fn]);
      acc[fm][fn] = mfma16(al[fm], bh[fn], acc[fm][fn]);
      acc[fm][fn] = mfma16(ah[fm], bl[fn], acc[fm][fn]);
    }
  #pragma unroll
  for (int fm = 0; fm < 2; ++fm)
    #pragma unroll
    for (int fn = 0; fn < 2; ++fn)
      #pragma unroll
      for (int i = 0; i < 4; ++i)
        S[wm*32 + fm*16 + lk*4 + i][wn*32 + fn*16 + lr] = acc[fm][fn][i];
  __syncthreads();
  float inv_eps = 2.0f / (float)(1 << (h >> 2));
  float effw = ggate[h] * wdist[h];
  const float is32 = 0.17677669529663687f;
  int row16 = t >> 4;
  int col = (t & 15) << 2;
  #pragma unroll
  for (int rep = 0; rep < 4; ++rep) {
    int rl = row16 + (rep << 4);
    int rowg = (it << 6) + rl;
    int colg = (jt << 6) + col;
    size_t base = ((size_t)h << 20) + ((size_t)rowg << 10) + colg;
    float4 w4 = ld4(wrel + base);
    float xa0 = xi[rl][0], xa1 = xi[rl][1], xa2 = xi[rl][2];
    short o16[4];
    #pragma unroll
    for (int bq = 0; bq < 4; ++bq) {
      int cl = col + bq;
      float dx = xa0 - xj[cl][0], dy = xa1 - xj[cl][1], dz = xa2 - xj[cl][2];
      float d2 = dx*dx + dy*dy + dz*dz;
      float dist = sqrtf(fmaxf(d2, 1e-12f));
      float f = dist / (10.0f + dist);
      float wv = (bq==0)?w4.x:(bq==1)?w4.y:(bq==2)?w4.z:w4.w;
      float m = (S[rl][cl] * is32 - wv - effw * f) * inv_eps;
      o16[bq] = (short)__float2int_rn(fminf(fmaxf(m * 256.f, -32000.f), 32000.f));
    }
    short4 q4o; q4o.x = o16[0]; q4o.y = o16[1]; q4o.z = o16[2]; q4o.w = o16[3];
    *(short4*)(Mq + base) = q4o;
  }
}

// ------- Sinkhorn iteration: 16-row blocks, XCD-pinned head mapping -------
__global__ __launch_bounds__(256) void sink_iter8(const short* __restrict__ Mq,
    const float* __restrict__ lvb, const float* __restrict__ mu,
    float* __restrict__ lu_out, float* __restrict__ part) {
  __shared__ float lds[4][1024];
  __shared__ float logmu[16];
  int id = blockIdx.x;
  int h = (((id >> 3) & 1) << 3) | (id & 7);
  int bt = id >> 4;
  int t = threadIdx.x, w = t >> 6, lane = t & 63;
  float eps = 0.5f * (float)(1 << (h >> 2));
  float fac = 1.f / (1.f + eps);
  const float qs = 1.f / 256.f;
  int rowbase = bt << 4;
  if (t < 16) logmu[t] = __logf(fmaxf(mu[(h << 10) + rowbase + t], 1e-8f));
  const short* Mh = Mq + ((size_t)h << 20);
  int ib = rowbase + (w << 2);
  short8 qa[4], qb[4];
  #pragma unroll
  for (int k = 0; k < 4; ++k) {
    const short* row = Mh + ((size_t)(ib + k) << 10) + (lane << 3);
    qa[k] = *(const short8*)row;
    qb[k] = *(const short8*)(row + 512);
  }
  float4 lv4[2][2], env[2][2];
  #pragma unroll
  for (int c = 0; c < 2; ++c) {
    const float* lp = lvb + (h << 10) + (c << 9) + (lane << 3);
    lv4[c][0] = ld4(lp);
    lv4[c][1] = ld4(lp + 4);
    #pragma unroll
    for (int hv = 0; hv < 2; ++hv) {
      env[c][hv].x = __expf(-lv4[c][hv].x); env[c][hv].y = __expf(-lv4[c][hv].y);
      env[c][hv].z = __expf(-lv4[c][hv].z); env[c][hv].w = __expf(-lv4[c][hv].w);
    }
  }
  float4 colacc[2][2];
  #pragma unroll
  for (int c = 0; c < 2; ++c)
    #pragma unroll
    for (int hv = 0; hv < 2; ++hv) colacc[c][hv] = make_float4(0.f,0.f,0.f,0.f);
  #pragma unroll
  for (int k = 0; k < 4; ++k) {
    short8 q0 = qa[k], q1 = qb[k];
    float4 e[2][2];
    e[0][0].x = __expf((float)q0[0]*qs + lv4[0][0].x);
    e[0][0].y = __expf((float)q0[1]*qs + lv4[0][0].y);
    e[0][0].z = __expf((float)q0[2]*qs + lv4[0][0].z);
    e[0][0].w = __expf((float)q0[3]*qs + lv4[0][0].w);
    e[0][1].x = __expf((float)q0[4]*qs + lv4[0][1].x);
    e[0][1].y = __expf((float)q0[5]*qs + lv4[0][1].y);
    e[0][1].z = __expf((float)q0[6]*qs + lv4[0][1].z);
    e[0][1].w = __expf((float)q0[7]*qs + lv4[0][1].w);
    e[1][0].x = __expf((float)q1[0]*qs + lv4[1][0].x);
    e[1][0].y = __expf((float)q1[1]*qs + lv4[1][0].y);
    e[1][0].z = __expf((float)q1[2]*qs + lv4[1][0].z);
    e[1][0].w = __expf((float)q1[3]*qs + lv4[1][0].w);
    e[1][1].x = __expf((float)q1[4]*qs + lv4[1][1].x);
    e[1][1].y = __expf((float)q1[5]*qs + lv4[1][1].y);
    e[1][1].z = __expf((float)q1[6]*qs + lv4[1][1].z);
    e[1][1].w = __expf((float)q1[7]*qs + lv4[1][1].w);
    float racc = ((e[0][0].x + e[0][0].y) + (e[0][0].z + e[0][0].w))
               + ((e[0][1].x + e[0][1].y) + (e[0][1].z + e[0][1].w))
               + ((e[1][0].x + e[1][0].y) + (e[1][0].z + e[1][0].w))
               + ((e[1][1].x + e[1][1].y) + (e[1][1].z + e[1][1].w));
    #pragma unroll
    for (int off = 1; off < 64; off <<= 1) racc += __shfl_xor(racc, off);
    float lu = fac * (logmu[(w << 2) + k] - __logf(racc));
    if (lane == 0) lu_out[(h << 10) + ib + k] = lu;
    float s1 = __expf(lu);
    #pragma unroll
    for (int c = 0; c < 2; ++c)
      #pragma unroll
      for (int hv = 0; hv < 2; ++hv) {
        colacc[c][hv].x += s1 * (e[c][hv].x * env[c][hv].x);
        colacc[c][hv].y += s1 * (e[c][hv].y * env[c][hv].y);
        colacc[c][hv].z += s1 * (e[c][hv].z * env[c][hv].z);
        colacc[c][hv].w += s1 * (e[c][hv].w * env[c][hv].w);
      }
  }
  #pragma unroll
  for (int c = 0; c < 2; ++c) {
    st4(&lds[w][(c << 9) + (lane << 3)], colacc[c][0]);
    st4(&lds[w][(c << 9) + (lane << 3) + 4], colacc[c][1]);
  }
  __syncthreads();
  #pragma unroll
  for (int c = 0; c < 4; ++c) {
    int j = t + (c << 8);
    float v = (lds[0][j] + lds[1][j]) + (lds[2][j] + lds[3][j]);
    part[(((size_t)(h << 6) + bt) << 10) + j] = v;
  }
}

// ------- Sinkhorn col finalize: lv = fac*(log(nu) - log(sum of 64 partials)) -------
__global__ __launch_bounds__(256) void sink_fin(const float* __restrict__ part,
    const float* __restrict__ nu, float* __restrict__ lvb) {
  int cx = blockIdx.x, h = blockIdx.y;
  int t = threadIdx.x;
  float eps = 0.5f * (float)(1 << (h >> 2));
  float fac = 1.f / (1.f + eps);
  int j = (cx << 8) + t;
  float sum = 0.f;
  #pragma unroll 16
  for (int b = 0; b < 64; ++b)
    sum += part[(((size_t)(h << 6) + b) << 10) + j];
  float lv = fac * (__logf(fmaxf(nu[(h << 10) + j], 1e-8f)) - __logf(sum));
  lvb[(h << 10) + j] = lv;
}

// ---- build Bt[h][48][1024] bf16 = [V^T | x^T | ones | 0] for the attn MFMA ----
__global__ __launch_bounds__(256) void attn_prep(const float* __restrict__ V,
    const float* __restrict__ xres, unsigned short* __restrict__ Bt) {
  int jb = blockIdx.x, h = blockIdx.y;
  int t = threadIdx.x;
  #pragma unroll
  for (int rep = 0; rep < 12; ++rep) {
    int idx = t + (rep << 8);
    int jl = idx & 63, c = idx >> 6;
    int j = (jb << 6) + jl;
    float val;
    if (c < 32)      val = V[((((size_t)h << 10) + j) << 5) + c];
    else if (c < 35) val = xres[j * 3 + (c - 32)];
    else if (c == 35) val = 1.f;
    else              val = 0.f;
    Bt[(((size_t)h * 48 + c) << 10) + j] = bf16r(val);
  }
}

// ---- attn via MFMA: O[32 x 48] = e[32 x 1024] @ Bt^T; rows normalized by ones-col ----
__global__ __launch_bounds__(256) void attn_out_v6(const short* __restrict__ Mq,
    const unsigned short* __restrict__ Bt, const float* __restrict__ lu_g,
    const float* __restrict__ lv_g, const float* __restrict__ G,
    float* __restrict__ o_buf, float* __restrict__ xc) {
  __shared__ float lv_s[1024];
  __shared__ float lu_s[32];
  __shared__ float red[3][64][24];
  __shared__ float rs_s[32];
  int rb = blockIdx.x, h = blockIdx.y;
  int t = threadIdx.x, w = t >> 6, lane = t & 63;
  int lr = lane & 15, lk = lane >> 4;
  int rowbase = rb << 5;
  ((float4*)lv_s)[t] = ld4(lv_g + (h << 10) + (t << 2));
  if (t < 32) lu_s[t] = lu_g[(h << 10) + rowbase + t];
  __syncthreads();
  const float qs = 1.f / 256.f;
  float lu0 = lu_s[lr], lu1 = lu_s[16 + lr];
  const short* Mh = Mq + ((size_t)h << 20) + ((size_t)rowbase << 10);
  const unsigned short* Bh = Bt + (((size_t)h * 48) << 10);
  f32x4 acc[2][3];
  #pragma unroll
  for (int i = 0; i < 2; ++i)
    #pragma unroll
    for (int j = 0; j < 3; ++j)
      #pragma unroll
      for (int r = 0; r < 4; ++r) acc[i][j][r] = 0.f;
  for (int step = 0; step < 8; ++step) {
    int ks = (step << 2) | w;
    int j0 = (ks << 5) + (lk << 3);
    short8 m0 = *(const short8*)(Mh + ((size_t)lr << 10) + j0);
    short8 m1 = *(const short8*)(Mh + ((size_t)(16 + lr) << 10) + j0);
    short8 a0, a1;
    #pragma unroll
    for (int i = 0; i < 8; ++i) {
      float lvv = lv_s[j0 + i];
      a0[i] = (short)bf16r(__expf((float)m0[i] * qs + lu0 + lvv));
      a1[i] = (short)bf16r(__expf((float)m1[i] * qs + lu1 + lvv));
    }
    short8 b0 = *(const short8*)(Bh + ((size_t)lr << 10) + j0);
    short8 b1 = *(const short8*)(Bh + ((size_t)(16 + lr) << 10) + j0);
    short8 b2 = *(const short8*)(Bh + ((size_t)(32 + lr) << 10) + j0);
    acc[0][0] = mfma16(a0, b0, acc[0][0]);
    acc[0][1] = mfma16(a0, b1, acc[0][1]);
    acc[0][2] = mfma16(a0, b2, acc[0][2]);
    acc[1][0] = mfma16(a1, b0, acc[1][0]);
    acc[1][1] = mfma16(a1, b1, acc[1][1]);
    acc[1][2] = mfma16(a1, b2, acc[1][2]);
  }
  if (w) {
    #pragma unroll
    for (int fm = 0; fm < 2; ++fm)
      #pragma unroll
      for (int fn = 0; fn < 3; ++fn)
        #pragma unroll
        for (int i = 0; i < 4; ++i)
          red[w - 1][lane][(fm * 3 + fn) * 4 + i] = acc[fm][fn][i];
  }
  __syncthreads();
  if (w == 0) {
    #pragma unroll
    for (int fm = 0; fm < 2; ++fm)
      #pragma unroll
      for (int fn = 0; fn < 3; ++fn)
        #pragma unroll
        for (int i = 0; i < 4; ++i)
          acc[fm][fn][i] += red[0][lane][(fm*3+fn)*4+i] + red[1][lane][(fm*3+fn)*4+i]
                          + red[2][lane][(fm*3+fn)*4+i];
    if (lr == 3) {
      #pragma unroll
      for (int fm = 0; fm < 2; ++fm)
        #pragma unroll
        for (int i = 0; i < 4; ++i)
          rs_s[fm*16 + lk*4 + i] = acc[fm][2][i];
    }
    #pragma unroll
    for (int fm = 0; fm < 2; ++fm)
      #pragma unroll
      for (int fn = 0; fn < 2; ++fn)
        #pragma unroll
        for (int i = 0; i < 4; ++i) {
          int rl = fm*16 + lk*4 + i;
          int row = rowbase + rl;
          int col = fn*16 + lr;
          float inv = 1.f / (rs_s[rl] + 1e-8f);
          size_t ga = ((size_t)row << 9) + h*32 + col;
          float g = G[ga];
          o_buf[ga] = acc[fm][fn][i] * inv / (1.f + __expf(-g));
        }
    if (lr < 3) {
      #pragma unroll
      for (int fm = 0; fm < 2; ++fm)
        #pragma unroll
        for (int i = 0; i < 4; ++i) {
          int rl = fm*16 + lk*4 + i;
          int row = rowbase + rl;
          xc[((size_t)((h << 10) + row)) * 3 + lr] = acc[fm][2][i] / (rs_s[rl] + 1e-8f);
        }
    }
  }
}

// ---------------- x_res update ----------------
__global__ void x_update(const float* __restrict__ xres, const float* __restrict__ xc,
    const float* __restrict__ gamma, float* __restrict__ xout) {
  int idx = blockIdx.x * 256 + threadIdx.x;
  if (idx >= 3072) return;
  float x = xres[idx];
  float s = x;
  #pragma unroll
  for (int hh = 0; hh < 16; ++hh) s += gamma[hh] * (x - xc[(size_t)hh * 3072 + idx]);
  xout[idx] = s;
}

// ---------------- o = a + b + c ----------------
__global__ __launch_bounds__(256) void add3(const float* __restrict__ a,
    const float* __restrict__ b, const float* __restrict__ c, float* __restrict__ o) {
  int i = (blockIdx.x * 256 + threadIdx.x) << 2;
  float4 va = ld4(a + i), vb = ld4(b + i), vc = ld4(c + i);
  st4(o + i, make_float4(va.x+vb.x+vc.x, va.y+vb.y+vc.y, va.z+vb.z+vc.z, va.w+vb.w+vc.w));
}

extern "C" void kernel_launch(void* const* d_in, const int* in_sizes, int n_in,
                              void* d_out, int out_size, void* d_ws, size_t ws_size,
                              hipStream_t stream) {
  const float* h_in    = (const float*)d_in[0];
  const float* x_res   = (const float*)d_in[1];
  const float* mu      = (const float*)d_in[2];
  const float* nu      = (const float*)d_in[3];
  const float* lv_prev = (const float*)d_in[5];
  const float* wrel    = (const float*)d_in[6];
  const float* wdist   = (const float*)d_in[7];
  const float* ggate   = (const float*)d_in[9];
  const float* lnaw    = (const float*)d_in[10];
  const float* lnab    = (const float*)d_in[11];
  const float* Wq      = (const float*)d_in[12];
  const float* Wk      = (const float*)d_in[13];
  const float* Wv      = (const float*)d_in[14];
  const float* Wg      = (const float*)d_in[15];
  const float* Wo      = (const float*)d_in[16];
  const float* gamma   = (const float*)d_in[17];
  const float* lnfw    = (const float*)d_in[18];
  const float* lnfb    = (const float*)d_in[19];
  const float* W1      = (const float*)d_in[20];
  const float* W3      = (const float*)d_in[21];
  const float* W2      = (const float*)d_in[22];

  float* out = (float*)d_out;
  float* OUT_H  = out;
  float* OUT_X  = out + 524288;
  float* OUT_LU = out + 527360;
  float* OUT_LV = out + 543744;   // working lv buffer

  if (ws_size < (size_t)19988480 * sizeof(float)) return;
  float* ws   = (float*)d_ws;
  float* Qb   = ws;                    // 524288 (H,N,32) f32
  float* Kb   = ws + 524288;           // 524288
  float* Vb   = ws + 1048576;          // 524288
  float* Gb   = ws + 1572864;          // 524288 (N,D) f32
  float* Mb   = ws + 2097152;          // Mq int16 = 16777216 shorts = first 8388608 floats
  float* part = ws + 18874368;         // 1048576 (H,64,N) col partials
  float* xcb  = ws + 19922944;         // 49152
  short* Mq   = (short*)Mb;
  // Phase-A overlays inside Mb (dead before build_M writes Mq):
  float* h_n = Mb;                                        // 1024x512 f32
  unsigned short* WqT = (unsigned short*)(Mb + 524288);
  unsigned short* WkT = (unsigned short*)(Mb + 786432);
  unsigned short* WvT = (unsigned short*)(Mb + 1048576);
  unsigned short* WgT = (unsigned short*)(Mb + 1310720);
  // bf16 hi/lo LN'd Q/K — beyond Mq's 8388608-float extent:
  unsigned short* Qhh = (unsigned short*)(Mb + 8388608);  // 262144 floats each
  unsigned short* Qll = (unsigned short*)(Mb + 8650752);
  unsigned short* Khh = (unsigned short*)(Mb + 8912896);
  unsigned short* Kll = (unsigned short*)(Mb + 9175040);  // ends 9437184
  // Bt overlays the (dead after build_M) Qhh region:
  unsigned short* Bt = (unsigned short*)(Mb + 8388608);   // 786432 shorts, ends 8781824
  // Phase-B overlays inside Mb (Mq dead after attn_out_v6):
  float* ABb = Mb + 4194304;                               // written after attn
  unsigned short* W1T = (unsigned short*)(Mb + 0);         // 2048x512 hi+lo = 1048576 floats
  unsigned short* W3T = (unsigned short*)(Mb + 1048576);
  unsigned short* W2T = (unsigned short*)(Mb + 2097152);   // 512x2048 hi+lo = 1048576 floats
  unsigned short* WoT = (unsigned short*)(Mb + 3145728);   // 512x512 hi+lo = 262144 floats
  float* Pa = Mb + 6291456;                                // 524288 f32
  float* Pb = Mb + 6815744;                                // 524288 f32
  // Other reuse:
  float* o_buf = part;                 // 1024x512 f32 (part dead after sink)
  float* h2  = Qb;
  float* ffb = Kb;

  // --- attention input projections (split-precision bf16 MFMA) ---
  ln_rows<<<NTOK, 256, 0, stream>>>(h_in, lnaw, lnab, h_n);
  {
    C4 c = { Wq, Wk, Wv, Wg, WqT, WkT, WvT, WgT };
    convT<<<dim3(8, 8, 4), 256, 0, stream>>>(c, 512, 512);
  }
  {
    P4 p = { WqT, WkT, WvT, WgT, Qb, Kb, Vb, Gb };
    gemm_mfma<0><<<dim3(8, 16, 4), 256, 0, stream>>>(h_n, p, 512, 512, 0);
  }
  qk_ln_split<<<dim3(2048, 2), 256, 0, stream>>>(Qb, Kb, Qhh, Qll, Khh, Kll);
  build_M<<<dim3(16, 16, 16), 256, 0, stream>>>(Qhh, Qll, Khh, Kll, wrel, x_res,
                                                wdist, ggate, Mq);
  attn_prep<<<dim3(16, 16), 256, 0, stream>>>(Vb, x_res, Bt);
  hipMemcpyAsync(OUT_LV, lv_prev, 16384 * sizeof(float), hipMemcpyDeviceToDevice, stream);
  for (int it = 0; it < 20; ++it) {
    sink_iter8<<<1024, 256, 0, stream>>>(Mq, OUT_LV, mu, OUT_LU, part);
    sink_fin<<<dim3(4, 16), 256, 0, stream>>>(part, nu, OUT_LV);
  }
  attn_out_v6<<<dim3(32, 16), 256, 0, stream>>>(Mq, Bt, OUT_LU, OUT_LV, Gb, o_buf, xcb);
  x_update<<<12, 256, 0, stream>>>(x_res, xcb, gamma, OUT_X);

  // --- output projection + FFN (weight convTs overwrite Mq region, now dead) ---
  {
    C4 c = { Wo, nullptr, nullptr, nullptr, WoT, nullptr, nullptr, nullptr };
    convT<<<dim3(8, 8, 1), 256, 0, stream>>>(c, 512, 512);
  }
  {
    C4 c = { W1, W3, nullptr, nullptr, W1T, W3T, nullptr, nullptr };
    convT<<<dim3(32, 8, 2), 256, 0, stream>>>(c, 512, 2048);
  }
  {
    C4 c = { W2, nullptr, nullptr, nullptr, W2T, nullptr, nullptr, nullptr };
    convT<<<dim3(8, 32, 1), 256, 0, stream>>>(c, 2048, 512);
  }
  {
    P4 p = { WoT, WoT, nullptr, nullptr, Pa, Pb, nullptr, nullptr };
    gemm_mfma<1><<<dim3(8, 16, 2), 256, 0, stream>>>(o_buf, p, 512, 512, 256);
  }
  ln_rows3<<<NTOK, 256, 0, stream>>>(Pa, Pb, h_in, lnfw, lnfb, h2, ffb);
  gemm_w13<<<dim3(32, 16), 256, 0, stream>>>(ffb, W1T, W3T, ABb);
  {
    P4 p = { W2T, W2T, nullptr, nullptr, Pa, Pb, nullptr, nullptr };
    gemm_mfma<1><<<dim3(8, 16, 2), 256, 0, stream>>>(ABb, p, 2048, 512, 1024);
  }
  add3<<<512, 256, 0, stream>>>(Pa, Pb, h2, OUT_H);
}